// Round 6
// baseline (251.027 us; speedup 1.0000x reference)
//
#include <hip/hip_runtime.h>
#include <math.h>
#include <stdint.h>

#define S_LEN   512
#define HORIZON 64
#define T_LEN   (S_LEN + HORIZON)
#define F_IN    4
#define IN_DIM  36   // F_IN + E
#define HID     32

typedef float v2f __attribute__((ext_vector_type(2)));

__device__ __forceinline__ float frcp(float x) { return __builtin_amdgcn_rcpf(x); }
__device__ __forceinline__ float fsig(float x) { return frcp(1.f + __expf(-x)); }
__device__ __forceinline__ float rdlane(float v, int l) {
    return __int_as_float(__builtin_amdgcn_readlane(__float_as_int(v), l));
}
__device__ __forceinline__ void pk_fma(v2f& acc, v2f a, v2f b) {
    asm("v_pk_fma_f32 %0, %1, %2, %0" : "+v"(acc) : "v"(a), "v"(b));
}

// DPP move with old=0.
#define DPP0(x, ctrl, rmask, bmask, bc) \
    __int_as_float(__builtin_amdgcn_update_dpp(0, __float_as_int(x), (ctrl), (rmask), (bmask), (bc)))

// ============ Kernel 1: the sequential recurrence (one wave) ============
// K-split layout: lane 2j+p owns ALL 4 gate rows of unit j (i,f,g,o =
// rows j, j+32, j+64, j+96) over K-half p (h[16p..16p+16)). One quad_perm
// exchange per gate merges halves; i,f,g,o end up local; both parities
// compute identical h (no exec-mask churn anywhere in the hot loop).
__global__ __launch_bounds__(64, 1) void deepar_seq(
    const float* __restrict__ X,    const float* __restrict__ y,
    const float* __restrict__ Xf,   const float* __restrict__ eps,
    const float* __restrict__ W_ye, const float* __restrict__ b_ye,
    const float* __restrict__ W_ih, const float* __restrict__ W_hh,
    const float* __restrict__ b_ih, const float* __restrict__ b_hh,
    const float* __restrict__ W_ef, const float* __restrict__ b_ef,
    const float* __restrict__ W_av, const float* __restrict__ b_av,
    const float* __restrict__ W_out, const float* __restrict__ b_out,
    const float* __restrict__ W_mu, const float* __restrict__ b_mu,
    const float* __restrict__ W_sig, const float* __restrict__ b_sig,
    float* __restrict__ out, float* __restrict__ hist2)
{
    const int lane = threadIdx.x;
    const int j    = lane >> 1;
    const int p    = lane & 1;

    // ---- LDS staging of all per-step inputs + h broadcast line ----
    __shared__ __align__(16) float Xall[T_LEN * F_IN];   // X then Xf, (t,4)
    __shared__ __align__(16) float ys[S_LEN];
    __shared__ __align__(16) float epss[T_LEN];
    __shared__ __align__(16) float h_lds[HID];

#pragma unroll
    for (int k = 0; k < 8; ++k)
        ((float4*)Xall)[lane + 64 * k] = ((const float4*)X)[lane + 64 * k];
    ((float4*)Xall)[512 + lane] = ((const float4*)Xf)[lane];
#pragma unroll
    for (int k = 0; k < 2; ++k)
        ((float4*)ys)[lane + 64 * k] = ((const float4*)y)[lane + 64 * k];
#pragma unroll
    for (int k = 0; k < 2; ++k)
        ((float4*)epss)[lane + 64 * k] = ((const float4*)eps)[lane + 64 * k];
    if (lane < 16)
        ((float4*)epss)[lane + 128] = ((const float4*)eps)[lane + 128];

    // ---- resident weights: 4 rows x 16 K-half floats ----
    const int rows0 = j, rows1 = j + 32, rows2 = j + 64, rows3 = j + 96;
    float whhq[4][16];
    {
        const int rr[4] = {rows0, rows1, rows2, rows3};
#pragma unroll
        for (int q = 0; q < 4; ++q)
#pragma unroll
            for (int m = 0; m < 4; ++m)
                ((float4*)whhq[q])[m] =
                    ((const float4*)(W_hh + rr[q] * HID + 16 * p))[m];
    }
    // ext pairs: (x0,x1),(x2,x3),(yt,1) slots; p=0 carries Wx, p=1 carries (u, bias)
    float ext[4][6];
    {
        const int rr[4] = {rows0, rows1, rows2, rows3};
#pragma unroll
        for (int q = 0; q < 4; ++q) {
            const int r = rr[q];
            if (p == 0) {
                ((float4*)ext[q])[0] = *((const float4*)(W_ih + r * IN_DIM));
                ext[q][4] = 0.f; ext[q][5] = 0.f;
            } else {
                ext[q][0] = ext[q][1] = ext[q][2] = ext[q][3] = 0.f;
                float u = 0.f, b = b_ih[r] + b_hh[r];
                for (int k = 0; k < 32; ++k) {
                    const float w = W_ih[r * IN_DIM + 4 + k];
                    u += W_ye[k] * w;
                    b += b_ye[k] * w;
                }
                ext[q][4] = u; ext[q][5] = b;
            }
        }
    }

    // collapsed-attention constants (uniform values)
    float A = 0.f, B = 0.f, C1 = 0.f, C2 = 0.f, C3 = 0.f, C4 = 0.f;
#pragma unroll
    for (int k = 0; k < 32; ++k) {
        const float wef = W_ef[k], bef = b_ef[k], wav = W_av[k];
        A  += wef * wav;           B  += bef * wav;
        C1 += wef * W_out[k];      C2 += bef * W_out[k];
        C3 += wef * W_out[32 + k]; C4 += bef * W_out[32 + k];
    }
    B  += b_av[0];
    C2 += b_out[0];
    const float bmu  = b_mu[0], bsig = b_sig[0];
    const float wmu_l  = p ? 0.f : W_mu[j];
    const float wsig_l = p ? 0.f : W_sig[j];

    __syncthreads();

    float h = 0.f, c = 0.f;
    const float4* hhalf = ((const float4*)h_lds) + 4 * p;

#define STEP_GATES(XV, YT, GI, GF, GG, GO)                                 \
    {                                                                      \
        const float4 hq0 = hhalf[0], hq1 = hhalf[1],                       \
                     hq2 = hhalf[2], hq3 = hhalf[3];                       \
        const v2f hp0 = {hq0.x, hq0.y}, hp1 = {hq0.z, hq0.w},              \
                  hp2 = {hq1.x, hq1.y}, hp3 = {hq1.z, hq1.w},              \
                  hp4 = {hq2.x, hq2.y}, hp5 = {hq2.z, hq2.w},              \
                  hp6 = {hq3.x, hq3.y}, hp7 = {hq3.z, hq3.w};              \
        const v2f eA = {(XV).x, (XV).y}, eB = {(XV).z, (XV).w},            \
                  eC = {(YT), 1.f};                                        \
        float full[4];                                                     \
        _Pragma("unroll")                                                  \
        for (int q = 0; q < 4; ++q) {                                      \
            const v2f* w = (const v2f*)whhq[q];                            \
            const v2f* e = (const v2f*)ext[q];                             \
            v2f A0 = w[0] * hp0, A1 = w[1] * hp1;                          \
            pk_fma(A0, w[2], hp2);  pk_fma(A1, w[3], hp3);                 \
            pk_fma(A0, w[4], hp4);  pk_fma(A1, w[5], hp5);                 \
            pk_fma(A0, w[6], hp6);  pk_fma(A1, w[7], hp7);                 \
            pk_fma(A0, e[0], eA);   pk_fma(A1, e[1], eB);                  \
            pk_fma(A0, e[2], eC);                                          \
            const v2f s = A0 + A1;                                         \
            const float part = s.x + s.y;                                  \
            full[q] = part + DPP0(part, 0xB1, 0xF, 0xF, false);            \
        }                                                                  \
        GI = full[0]; GF = full[1]; GG = full[2]; GO = full[3];            \
    }

#define STEP_NONLIN(GI, GF, GG, GO)                                        \
    {                                                                      \
        const float si = fsig(GI);                                         \
        const float sf = fsig(GF);                                         \
        const float tg = fmaf(2.f, fsig(2.f * (GG)), -1.f);                \
        const float so = fsig(GO);                                         \
        c = sf * c + si * tg;                                              \
        h = so * fmaf(2.f, fsig(2.f * c), -1.f);                           \
    }

    // ---------- Phase A: t = 0..510 — LSTM cell only; outputs deferred ----------
#pragma unroll 4
    for (int t = 0; t < S_LEN - 1; ++t) {
        const float4 xv = ((const float4*)Xall)[t];
        const float  yt = ys[t];
        h_lds[j] = h;                       // both parities write the same value

        float gi, gf, gg, go;
        STEP_GATES(xv, yt, gi, gf, gg, go);
        STEP_NONLIN(gi, gf, gg, go);

        hist2[t * 64 + lane] = h;           // even entries (lane 2j) hold h_j
    }

    // ---------- Phase B: t = 511..575 — full step (feedback needed) ----------
    float ynext = 0.f;
    const float y511 = ys[S_LEN - 1];
#pragma unroll 1
    for (int t = S_LEN - 1; t < T_LEN; ++t) {
        const float4 xv   = ((const float4*)Xall)[t];
        const float eps_t = epss[t];
        const float yin   = (t == S_LEN - 1) ? y511 : ynext;
        h_lds[j] = h;

        float gi, gf, gg, go;
        STEP_GATES(xv, yin, gi, gf, gg, go);
        STEP_NONLIN(gi, gf, gg, go);

        // collapsed attention (exclusive prefix over elements j at even lanes)
        const float av   = __expf(h * A + B);
        const float av_e = p ? 0.f : av;
        const float avh  = av_e * h;
        float sP = av_e, sQ = avh;
        sP += DPP0(sP, 0x112, 0xF, 0xF, true);  sQ += DPP0(sQ, 0x112, 0xF, 0xF, true);
        sP += DPP0(sP, 0x114, 0xF, 0xF, true);  sQ += DPP0(sQ, 0x114, 0xF, 0xF, true);
        sP += DPP0(sP, 0x118, 0xF, 0xF, true);  sQ += DPP0(sQ, 0x118, 0xF, 0xF, true);
        float tP = DPP0(sP, 0x111, 0xF, 0xF, true), tQ = DPP0(sQ, 0x111, 0xF, 0xF, true);
        sP += DPP0(tP, 0x142, 0xA, 0xF, true);  sQ += DPP0(tQ, 0x142, 0xA, 0xF, true);
        tP = DPP0(sP, 0x111, 0xF, 0xF, true);   tQ = DPP0(sQ, 0x111, 0xF, 0xF, true);
        sP += DPP0(tP, 0x143, 0xC, 0xF, true);  sQ += DPP0(tQ, 0x143, 0xC, 0xF, true);

        const float P = sP - av_e, Q = sQ - avh;
        const float rden = frcp(P + 1e-9f);
        const float ex = __expf(2.f * (h * C1 + C2 + (Q * C3 + P * C4) * rden));
        const float outv = (ex - 1.f) * frcp(ex + 1.f);

        // mu / sigma: DPP tree-reduce, total in lane 63
        float pm = outv * wmu_l, ps = outv * wsig_l;
        pm += DPP0(pm, 0xB1,  0xF, 0xF, false);  ps += DPP0(ps, 0xB1,  0xF, 0xF, false);
        pm += DPP0(pm, 0x4E,  0xF, 0xF, false);  ps += DPP0(ps, 0x4E,  0xF, 0xF, false);
        pm += DPP0(pm, 0x141, 0xF, 0xF, false);  ps += DPP0(ps, 0x141, 0xF, 0xF, false);
        pm += DPP0(pm, 0x140, 0xF, 0xF, false);  ps += DPP0(ps, 0x140, 0xF, 0xF, false);
        pm += DPP0(pm, 0x142, 0xA, 0xF, true);   ps += DPP0(ps, 0x142, 0xA, 0xF, true);
        pm += DPP0(pm, 0x143, 0xC, 0xF, true);   ps += DPP0(ps, 0x143, 0xC, 0xF, true);

        const float mu    = rdlane(pm, 63) + bmu;
        const float sigma = __logf(1.f + __expf(rdlane(ps, 63) + bsig)) + 1e-6f;
        const float ynew  = mu + sigma * eps_t;
        ynext = ynew;

        if (lane == 0) {
            out[HORIZON + t]         = mu;
            out[HORIZON + T_LEN + t] = sigma;
            if (t >= S_LEN - 1 && t < S_LEN - 1 + HORIZON)
                out[t - (S_LEN - 1)] = ynew;
        }
    }
#undef STEP_GATES
#undef STEP_NONLIN
}

// ============ Kernel 2: parallel deferred outputs for t = 0..510 ============
__global__ __launch_bounds__(256) void deepar_par(
    const float* __restrict__ hist2,
    const float* __restrict__ W_ef, const float* __restrict__ b_ef,
    const float* __restrict__ W_av, const float* __restrict__ b_av,
    const float* __restrict__ W_out, const float* __restrict__ b_out,
    const float* __restrict__ W_mu, const float* __restrict__ b_mu,
    const float* __restrict__ W_sig, const float* __restrict__ b_sig,
    float* __restrict__ out)
{
    const int gid = (blockIdx.x * 256 + threadIdx.x) >> 5;   // one step per 32 lanes
    const int l   = threadIdx.x & 31;
    if (gid >= S_LEN - 1) return;

    float A = 0.f, B = 0.f, C1 = 0.f, C2 = 0.f, C3 = 0.f, C4 = 0.f;
#pragma unroll
    for (int k = 0; k < 32; ++k) {
        const float wef = W_ef[k], bef = b_ef[k], wav = W_av[k];
        A  += wef * wav;           B  += bef * wav;
        C1 += wef * W_out[k];      C2 += bef * W_out[k];
        C3 += wef * W_out[32 + k]; C4 += bef * W_out[32 + k];
    }
    B  += b_av[0];
    C2 += b_out[0];

    const float hj  = hist2[gid * 64 + 2 * l];   // even entries hold true h
    const float av  = __expf(hj * A + B);
    const float avh = av * hj;
    float sP = av, sQ = avh;
#pragma unroll
    for (int d = 1; d < 32; d <<= 1) {
        const float pP = __shfl_up(sP, d, 32);
        const float pQ = __shfl_up(sQ, d, 32);
        if (l >= d) { sP += pP; sQ += pQ; }
    }
    const float P = sP - av, Q = sQ - avh;
    const float rden = frcp(P + 1e-9f);
    const float ex = __expf(2.f * (hj * C1 + C2 + (Q * C3 + P * C4) * rden));
    const float outv = (ex - 1.f) * frcp(ex + 1.f);

    float pm = outv * W_mu[l], ps = outv * W_sig[l];
#pragma unroll
    for (int m = 16; m >= 1; m >>= 1) {
        pm += __shfl_xor(pm, m, 32);
        ps += __shfl_xor(ps, m, 32);
    }
    if (l == 0) {
        out[HORIZON + gid]         = pm + b_mu[0];
        out[HORIZON + T_LEN + gid] = __logf(1.f + __expf(ps + b_sig[0])) + 1e-6f;
    }
}

extern "C" void kernel_launch(void* const* d_in, const int* in_sizes, int n_in,
                              void* d_out, int out_size, void* d_ws, size_t ws_size,
                              hipStream_t stream) {
    float* hist2 = (float*)d_ws;   // (S_LEN-1) x 64 floats

    deepar_seq<<<1, 64, 0, stream>>>(
        (const float*)d_in[0],  (const float*)d_in[1],  (const float*)d_in[2],
        (const float*)d_in[3],  (const float*)d_in[4],  (const float*)d_in[5],
        (const float*)d_in[6],  (const float*)d_in[7],  (const float*)d_in[8],
        (const float*)d_in[9],  (const float*)d_in[10], (const float*)d_in[11],
        (const float*)d_in[12], (const float*)d_in[13], (const float*)d_in[14],
        (const float*)d_in[15], (const float*)d_in[16], (const float*)d_in[17],
        (const float*)d_in[18], (const float*)d_in[19], (float*)d_out, hist2);

    const int groups = S_LEN - 1;
    const int blocks = (groups * 32 + 255) / 256;
    deepar_par<<<blocks, 256, 0, stream>>>(
        hist2,
        (const float*)d_in[10], (const float*)d_in[11],
        (const float*)d_in[12], (const float*)d_in[13],
        (const float*)d_in[14], (const float*)d_in[15],
        (const float*)d_in[16], (const float*)d_in[17],
        (const float*)d_in[18], (const float*)d_in[19], (float*)d_out);
}